// Round 16
// baseline (160.477 us; speedup 1.0000x reference)
//
#include <hip/hip_runtime.h>
#include <hip/hip_bf16.h>

#define Tsz 2048
#define Hsz 768
#define NHsz 12
#define HDsz 64

typedef unsigned short u16;
typedef unsigned int u32;
typedef __attribute__((ext_vector_type(8))) short bf16x8;
typedef __attribute__((ext_vector_type(4))) float f32x4;
typedef __attribute__((ext_vector_type(4))) u16 u16x4;

__device__ __forceinline__ u16 f2bf(float f) {   // HW convert (RTNE)
    union { __hip_bfloat16 h; u16 u; } c;
    c.h = __float2bfloat16(f);
    return c.u;
}

__device__ __forceinline__ void glds16(const void* src, void* ldsbase) {
    __builtin_amdgcn_global_load_lds(
        (const __attribute__((address_space(1))) u32*)src,
        (__attribute__((address_space(3))) u32*)ldsbase, 16, 0, 0);
}

#define BAR() do { asm volatile("" ::: "memory"); \
                   __builtin_amdgcn_s_barrier();  \
                   asm volatile("" ::: "memory"); } while (0)

// [rows][64] bf16 tile, 128B rows, 8 chunks, chunk-XOR (row&7)
#define LDSFRAG(base, row, c) \
    (*(const bf16x8*)((const char*)(base) + (row)*128 + ((((c) << 4)) ^ (((row) & 7) << 4))))

// ---------------------------------------------------------------------------
// Kernel 0: fp32 -> bf16 conversion of X and Wq/Wk/Wv (unchanged).
// ---------------------------------------------------------------------------
__global__ __launch_bounds__(256) void to_bf16(
    const float* __restrict__ X,
    const float* __restrict__ Wq, const float* __restrict__ Wk,
    const float* __restrict__ Wv,
    u16* __restrict__ xb, u16* __restrict__ wb)
{
    const int bx = blockIdx.x, tid = threadIdx.x;
    const float* src;
    u16* dst;
    size_t off;
    if (bx < 768) {
        src = X; dst = xb;
        off = ((size_t)bx * 256 + tid) * 32;
    } else {
        int r = bx - 768;
        int wsel = r / 72, lr = r % 72;
        src = (wsel == 0) ? Wq : (wsel == 1) ? Wk : Wv;
        dst = wb + (size_t)wsel * (Hsz * Hsz);
        off = ((size_t)lr * 256 + tid) * 32;
    }
    #pragma unroll
    for (int c = 0; c < 4; ++c) {
        float4 a = *(const float4*)(src + off + c * 8);
        float4 b = *(const float4*)(src + off + c * 8 + 4);
        bf16x8 v;
        v[0] = (short)f2bf(a.x); v[1] = (short)f2bf(a.y);
        v[2] = (short)f2bf(a.z); v[3] = (short)f2bf(a.w);
        v[4] = (short)f2bf(b.x); v[5] = (short)f2bf(b.y);
        v[6] = (short)f2bf(b.z); v[7] = (short)f2bf(b.w);
        *(bf16x8*)(dst + off + c * 8) = v;
    }
}

// ---------------------------------------------------------------------------
// Kernel 1: QKV projection (unchanged round-15 version, XCD-chunked grid).
// ---------------------------------------------------------------------------
__global__ __launch_bounds__(256) void qkv_gemm(
    const u16* __restrict__ xb, const u16* __restrict__ wb,
    const float* __restrict__ bq, const float* __restrict__ bk,
    const float* __restrict__ bv,
    u16* __restrict__ q_ws, u16* __restrict__ k_ws, u16* __restrict__ vt_ws)
{
    const int tid = threadIdx.x;
    const int w = tid >> 6, l = tid & 63, lg = l >> 4, lh = l & 15;
    const int wg = blockIdx.x;                 // 0..1151
    const int swzb = (wg & 7) * 144 + (wg >> 3);
    const int nb = swzb % 18;
    const int m0 = (swzb / 18) * 128;
    const int z = nb / 6;
    const int n0l = (nb % 6) * 128;
    const u16* Wb = wb + (size_t)z * (Hsz * Hsz);
    const float* bias = (z == 0) ? bq : (z == 1) ? bk : bv;

    __shared__ __align__(16) u16 Xs[2][128 * 64];
    __shared__ __align__(16) u16 Ws[2][128 * 64];

    const int wm = w >> 1, wn = w & 1;

    f32x4 acc[4][4];
    #pragma unroll
    for (int i = 0; i < 4; ++i)
        #pragma unroll
        for (int j = 0; j < 4; ++j)
            acc[i][j] = (f32x4){0.f, 0.f, 0.f, 0.f};

    auto stage = [&](int buf, int k0) {
        #pragma unroll
        for (int p = 0; p < 4; ++p) {
            int id = w * 256 + p * 64 + l;
            int r = id >> 3, c8 = id & 7;
            int cswz = c8 ^ (r & 7);
            glds16(xb + (size_t)(m0 + r) * Hsz + k0 + cswz * 8,
                   &Xs[buf][(w * 256 + p * 64) * 8]);
            glds16(Wb + (size_t)(n0l + r) * Hsz + k0 + cswz * 8,
                   &Ws[buf][(w * 256 + p * 64) * 8]);
        }
    };

    stage(0, 0);
    asm volatile("s_waitcnt vmcnt(0)" ::: "memory");
    BAR();

    #pragma unroll 1
    for (int ks = 0; ks < 12; ++ks) {
        const int cur = ks & 1;
        if (ks < 11) {
            stage(cur ^ 1, (ks + 1) * 64);
            asm volatile("s_waitcnt vmcnt(8)" ::: "memory");
        } else {
            asm volatile("s_waitcnt vmcnt(0)" ::: "memory");
        }
        BAR();

        __builtin_amdgcn_s_setprio(1);
        #pragma unroll
        for (int s = 0; s < 2; ++s) {
            bf16x8 af[4], bfr[4];
            #pragma unroll
            for (int tq = 0; tq < 4; ++tq) {
                af[tq]  = LDSFRAG(Xs[cur], wm * 64 + tq * 16 + lh, 4 * s + lg);
                bfr[tq] = LDSFRAG(Ws[cur], wn * 64 + tq * 16 + lh, 4 * s + lg);
            }
            if (z <= 1) {
                #pragma unroll
                for (int mt = 0; mt < 4; ++mt)
                    #pragma unroll
                    for (int nt = 0; nt < 4; ++nt)
                        acc[mt][nt] = __builtin_amdgcn_mfma_f32_16x16x32_bf16(
                            bfr[nt], af[mt], acc[mt][nt], 0, 0, 0);
            } else {
                #pragma unroll
                for (int mt = 0; mt < 4; ++mt)
                    #pragma unroll
                    for (int nt = 0; nt < 4; ++nt)
                        acc[mt][nt] = __builtin_amdgcn_mfma_f32_16x16x32_bf16(
                            af[mt], bfr[nt], acc[mt][nt], 0, 0, 0);
            }
        }
        __builtin_amdgcn_s_setprio(0);
        BAR();
    }

    if (z <= 1) {
        u16* outp = (z == 0) ? q_ws : k_ws;
        #pragma unroll
        for (int mt = 0; mt < 4; ++mt) {
            int m = m0 + wm * 64 + mt * 16 + lh;
            int bb = m >> 11, t = m & 2047;
            #pragma unroll
            for (int nt = 0; nt < 4; ++nt) {
                int nbase = n0l + wn * 64 + nt * 16 + lg * 4;
                int hh = nbase >> 6, d0 = nbase & 63;
                f32x4 b4 = *(const f32x4*)(bias + nbase);
                u16x4 pk;
                #pragma unroll
                for (int r = 0; r < 4; ++r) pk[r] = f2bf(acc[mt][nt][r] + b4[r]);
                *(u16x4*)(outp + ((size_t)(bb * NHsz + hh) * Tsz + t) * HDsz + d0) = pk;
            }
        }
    } else {
        #pragma unroll
        for (int nt = 0; nt < 4; ++nt) {
            int nloc = n0l + wn * 64 + nt * 16 + lh;
            float bval = bias[nloc];
            int hh = nloc >> 6, d = nloc & 63;
            #pragma unroll
            for (int mt = 0; mt < 4; ++mt) {
                int t0m = m0 + wm * 64 + mt * 16 + lg * 4;
                int bb = t0m >> 11, t0 = t0m & 2047;
                u16x4 pk;
                #pragma unroll
                for (int r = 0; r < 4; ++r) pk[r] = f2bf(acc[mt][nt][r] + bval);
                *(u16x4*)(vt_ws + ((size_t)(bb * NHsz + hh) * HDsz + d) * Tsz + t0) = pk;
            }
        }
    }
}

// ---------------------------------------------------------------------------
// Kernel 2: causal flash attention, round 16.
// R13/R15 structure with FIXED-MAX softmax: p = exp2(sv - 16). Valid scores
// are input-bounded (|sv| << 16); masked -> exp2(-huge) = exact 0. The shift
// cancels in O/l2. Removes per-tile: max chain, 2 max-shuffles, vote,
// rescale branch + corr shuffles + o-rescale, AND the per-tile l2 shuffles
// (l2 stays lane-local; cross-lane reduce once in epilogue).
// ---------------------------------------------------------------------------
__global__ __launch_bounds__(256) void attn_mfma(
    const u16* __restrict__ q_ws, const u16* __restrict__ k_ws,
    const u16* __restrict__ vt_ws, const float* __restrict__ am,
    float* __restrict__ out)
{
    const int tid = threadIdx.x;
    const int w = tid >> 6, l = tid & 63, lg = l >> 4, lh = l & 15;
    const int wg = blockIdx.x;
    const int swz = (wg & 7) * 96 + (wg >> 3);
    const int bx = swz & 15;
    const int grp = swz >> 4;          // 0..47
    const int h = grp % NHsz, b = grp / NHsz;
    const int bh = b * NHsz + h;

    const u16* Qb = q_ws + (size_t)bh * Tsz * HDsz;
    const u16* Kb = k_ws + (size_t)bh * Tsz * HDsz;
    const u16* Vb = vt_ws + (size_t)bh * HDsz * Tsz;   // [d][t]
    const float* amb = am + (size_t)b * Tsz;

    __shared__ __align__(16) u16 Ks[2][64 * 64];
    __shared__ __align__(16) u16 Vs[2][64 * 64];       // [d][kv] layout
    __shared__ __align__(16) u16 Ps[4][16 * 64];       // per-wave, swizzled
    __shared__ __align__(16) float ambs[Tsz];

    const float LOG2E  = 1.44269504f;
    const float SCALE2 = 0.125f * 1.44269504f;
    const float MFIX   = 16.0f;        // fixed softmax shift (exp2 domain)
    const f32x4 zero4 = {0.f, 0.f, 0.f, 0.f};
    u16* myP = &Ps[w][0];
    const int srcbase = l & 0x30;
    const int qo = lg * 4;

    const int qt_hi = 16 + bx, qt_lo = 15 - bx;
    const int q0h = qt_hi * 64 + w * 16;
    const int q0l = qt_lo * 64 + w * 16;
    const int qrow_h = q0h + lh, qrow_l = q0l + lh;

    // ---- stage mask (8KB) + K/V tile 0 + Q fragments ----
    #pragma unroll
    for (int i = 0; i < 2; ++i)
        glds16(amb + (size_t)(i * 256 + tid) * 4, ambs + (i * 256 + w * 64) * 4);
    #pragma unroll
    for (int p = 0; p < 2; ++p) {
        int id = w * 128 + p * 64 + l;
        int r = id >> 3, c8 = id & 7;
        int cswz = c8 ^ (r & 7);
        glds16(Kb + (size_t)r * HDsz + cswz * 8, &Ks[0][(w * 128 + p * 64) * 8]);
        glds16(Vb + (size_t)r * Tsz + cswz * 8, &Vs[0][(w * 128 + p * 64) * 8]);
    }
    bf16x8 qfh0 = *(const bf16x8*)(Qb + (size_t)(q0h + lh) * HDsz + lg * 8);
    bf16x8 qfh1 = *(const bf16x8*)(Qb + (size_t)(q0h + lh) * HDsz + lg * 8 + 32);
    bf16x8 qfl0 = *(const bf16x8*)(Qb + (size_t)(q0l + lh) * HDsz + lg * 8);
    bf16x8 qfl1 = *(const bf16x8*)(Qb + (size_t)(q0l + lh) * HDsz + lg * 8 + 32);
    asm volatile("s_waitcnt vmcnt(0)" ::: "memory");
    __syncthreads();
    #pragma unroll
    for (int i = 0; i < 8; ++i) ambs[tid * 8 + i] *= LOG2E;
    __syncthreads();

    f32x4 oh[4], ol[4];
    #pragma unroll
    for (int n = 0; n < 4; ++n) { oh[n] = zero4; ol[n] = zero4; }
    float l2h = 0.f, l2l = 0.f;        // lane-local partial sums

    // one Q-tile phase against the staged tile [kv0, kv0+64)
    auto phase = [&](const bf16x8& qf0, const bf16x8& qf1, int qrow,
                     f32x4* o, float& l2,
                     bool diag, const u16* Ksb, const u16* Vsb, int kv0) {
        // ---- S^T = K @ Q^T ----
        f32x4 st[4];
        __builtin_amdgcn_s_setprio(1);
        if (!diag) {
            #pragma unroll
            for (int n = 0; n < 4; ++n) {
                int row = n * 16 + lh;
                bf16x8 kf0 = LDSFRAG(Ksb, row, lg);
                bf16x8 kf1 = LDSFRAG(Ksb, row, 4 + lg);
                f32x4 c = __builtin_amdgcn_mfma_f32_16x16x32_bf16(kf0, qf0, zero4, 0, 0, 0);
                st[n] = __builtin_amdgcn_mfma_f32_16x16x32_bf16(kf1, qf1, c, 0, 0, 0);
            }
        } else {
            #pragma unroll
            for (int n = 0; n < 4; ++n) {
                st[n] = zero4;
                if (n <= w) {
                    int row = n * 16 + lh;
                    bf16x8 kf0 = LDSFRAG(Ksb, row, lg);
                    bf16x8 kf1 = LDSFRAG(Ksb, row, 4 + lg);
                    f32x4 c = __builtin_amdgcn_mfma_f32_16x16x32_bf16(kf0, qf0, zero4, 0, 0, 0);
                    st[n] = __builtin_amdgcn_mfma_f32_16x16x32_bf16(kf1, qf1, c, 0, 0, 0);
                }
            }
        }
        __builtin_amdgcn_s_setprio(0);

        // ---- fixed-max softmax: p = exp2(sv - MFIX), lane-local sum ----
        float pvv[16];
        float ps = 0.f;
        if (!diag) {
            #pragma unroll
            for (int n = 0; n < 4; ++n) {
                f32x4 a4 = *(const f32x4*)(ambs + kv0 + n * 16 + lg * 4);
                #pragma unroll
                for (int r = 0; r < 4; ++r) {
                    float sv = fmaf(st[n][r], SCALE2, a4[r]);
                    float p = exp2f(sv - MFIX);
                    pvv[n * 4 + r] = p;
                    ps += p;
                }
            }
        } else {
            #pragma unroll
            for (int n = 0; n < 4; ++n) {
                f32x4 a4 = *(const f32x4*)(ambs + kv0 + n * 16 + lg * 4);
                #pragma unroll
                for (int r = 0; r < 4; ++r) {
                    int kvj = kv0 + n * 16 + lg * 4 + r;
                    float sv = (kvj > qrow) ? -1e30f : fmaf(st[n][r], SCALE2, a4[r]);
                    float p = exp2f(sv - MFIX);
                    pvv[n * 4 + r] = p;
                    ps += p;
                }
            }
        }
        l2 += ps;

        // ---- write P (4x b64, chunk-XOR swizzled [16 q][64 kv]) ----
        #pragma unroll
        for (int n = 0; n < 4; ++n) {
            u16x4 v;
            v[0] = f2bf(pvv[n * 4 + 0]); v[1] = f2bf(pvv[n * 4 + 1]);
            v[2] = f2bf(pvv[n * 4 + 2]); v[3] = f2bf(pvv[n * 4 + 3]);
            int chunk = 2 * n + (lg >> 1);
            int byteoff = lh * 128 + ((chunk ^ (lh & 7)) << 4) + ((lg & 1) << 3);
            *(u16x4*)((char*)myP + byteoff) = v;
        }

        // ---- O += P V ----
        const int smaxv = (diag && w < 2) ? 0 : 1;
        __builtin_amdgcn_s_setprio(1);
        #pragma unroll
        for (int s = 0; s < 2; ++s) {
            if (s <= smaxv) {
                int chunk = (4 * s + lg) ^ (lh & 7);
                bf16x8 pf = *(const bf16x8*)((const char*)myP + lh * 128 + (chunk << 4));
                #pragma unroll
                for (int n = 0; n < 4; ++n) {
                    bf16x8 vf = LDSFRAG(Vsb, n * 16 + lh, 4 * s + lg);
                    o[n] = __builtin_amdgcn_mfma_f32_16x16x32_bf16(pf, vf, o[n], 0, 0, 0);
                }
            }
        }
        __builtin_amdgcn_s_setprio(0);
    };

    #pragma unroll 1
    for (int kt = 0; kt <= qt_hi; ++kt) {
        const int cur = kt & 1;
        const int kv0 = kt * 64;

        if (kt < qt_hi) {
            const int kv1 = kv0 + 64;
            #pragma unroll
            for (int p = 0; p < 2; ++p) {
                int id = w * 128 + p * 64 + l;
                int r = id >> 3, c8 = id & 7;
                int cswz = c8 ^ (r & 7);
                glds16(Kb + (size_t)(kv1 + r) * HDsz + cswz * 8,
                       &Ks[cur ^ 1][(w * 128 + p * 64) * 8]);
                glds16(Vb + (size_t)r * Tsz + kv1 + cswz * 8,
                       &Vs[cur ^ 1][(w * 128 + p * 64) * 8]);
            }
            asm volatile("s_waitcnt vmcnt(4)" ::: "memory");
        } else {
            asm volatile("s_waitcnt vmcnt(0)" ::: "memory");
        }
        BAR();   // tile kt staged, all waves

        const u16* Ksb = &Ks[cur][0];
        const u16* Vsb = &Vs[cur][0];

        // hi Q-tile: always active
        phase(qfh0, qfh1, qrow_h, oh, l2h, kt == qt_hi, Ksb, Vsb, kv0);
        // lo Q-tile: active while kt <= qt_lo (block-uniform predicate)
        if (kt <= qt_lo)
            phase(qfl0, qfl1, qrow_l, ol, l2l, kt == qt_lo, Ksb, Vsb, kv0);

        BAR();   // all reads of buf[cur] done before next prefetch overwrites
    }

    // ---- epilogue: cross-lane l2 reduce (once), normalize, write ----
    l2h += __shfl_xor(l2h, 16);
    l2h += __shfl_xor(l2h, 32);
    l2l += __shfl_xor(l2l, 16);
    l2l += __shfl_xor(l2l, 32);
    {
        float linv[4];
        #pragma unroll
        for (int r = 0; r < 4; ++r)
            linv[r] = 1.0f / __shfl(l2h, srcbase | (qo + r));
        float* ob = out + ((size_t)(b * Tsz + q0h + qo)) * Hsz + h * HDsz + lh;
        #pragma unroll
        for (int r = 0; r < 4; ++r)
            #pragma unroll
            for (int n = 0; n < 4; ++n)
                ob[r * Hsz + n * 16] = oh[n][r] * linv[r];
    }
    {
        float linv[4];
        #pragma unroll
        for (int r = 0; r < 4; ++r)
            linv[r] = 1.0f / __shfl(l2l, srcbase | (qo + r));
        float* ob = out + ((size_t)(b * Tsz + q0l + qo)) * Hsz + h * HDsz + lh;
        #pragma unroll
        for (int r = 0; r < 4; ++r)
            #pragma unroll
            for (int n = 0; n < 4; ++n)
                ob[r * Hsz + n * 16] = ol[n][r] * linv[r];
    }
}

extern "C" void kernel_launch(void* const* d_in, const int* in_sizes, int n_in,
                              void* d_out, int out_size, void* d_ws, size_t ws_size,
                              hipStream_t stream) {
    const float* X  = (const float*)d_in[0];
    const float* am = (const float*)d_in[1];
    const float* Wq = (const float*)d_in[2];
    const float* bq = (const float*)d_in[3];
    const float* Wk = (const float*)d_in[4];
    const float* bk = (const float*)d_in[5];
    const float* Wv = (const float*)d_in[6];
    const float* bv = (const float*)d_in[7];
    float* out = (float*)d_out;

    const size_t per = (size_t)8192 * Hsz;
    u16* q_ws  = (u16*)d_ws;
    u16* k_ws  = q_ws + per;
    u16* vt_ws = k_ws + per;

    u16* xb = (u16*)d_out;
    u16* wb = xb + per;

    to_bf16<<<dim3(984), 256, 0, stream>>>(X, Wq, Wk, Wv, xb, wb);

    qkv_gemm<<<dim3(1152), 256, 0, stream>>>(xb, wb, bq, bk, bv, q_ws, k_ws, vt_ws);

    attn_mfma<<<dim3(768), 256, 0, stream>>>(q_ws, k_ws, vt_ws, am, out);
}

// Round 17
// 139.883 us; speedup vs baseline: 1.1472x; 1.1472x over previous
//
#include <hip/hip_runtime.h>
#include <hip/hip_bf16.h>

#define Tsz 2048
#define Hsz 768
#define NHsz 12
#define HDsz 64

typedef unsigned short u16;
typedef unsigned int u32;
typedef __attribute__((ext_vector_type(8))) short bf16x8;
typedef __attribute__((ext_vector_type(4))) float f32x4;
typedef __attribute__((ext_vector_type(4))) u16 u16x4;

__device__ __forceinline__ u16 f2bf(float f) {   // HW convert (RTNE)
    union { __hip_bfloat16 h; u16 u; } c;
    c.h = __float2bfloat16(f);
    return c.u;
}

__device__ __forceinline__ void glds16(const void* src, void* ldsbase) {
    __builtin_amdgcn_global_load_lds(
        (const __attribute__((address_space(1))) u32*)src,
        (__attribute__((address_space(3))) u32*)ldsbase, 16, 0, 0);
}

#define BAR() do { asm volatile("" ::: "memory"); \
                   __builtin_amdgcn_s_barrier();  \
                   asm volatile("" ::: "memory"); } while (0)

// [rows][64] bf16 tile, 128B rows, 8 chunks, chunk-XOR (row&7)
#define LDSFRAG(base, row, c) \
    (*(const bf16x8*)((const char*)(base) + (row)*128 + ((((c) << 4)) ^ (((row) & 7) << 4))))

// ---------------------------------------------------------------------------
// Kernel 0: fp32 -> bf16 conversion of X and Wq/Wk/Wv.
// ---------------------------------------------------------------------------
__global__ __launch_bounds__(256) void to_bf16(
    const float* __restrict__ X,
    const float* __restrict__ Wq, const float* __restrict__ Wk,
    const float* __restrict__ Wv,
    u16* __restrict__ xb, u16* __restrict__ wb)
{
    const int bx = blockIdx.x, tid = threadIdx.x;
    const float* src;
    u16* dst;
    size_t off;
    if (bx < 768) {
        src = X; dst = xb;
        off = ((size_t)bx * 256 + tid) * 32;
    } else {
        int r = bx - 768;
        int wsel = r / 72, lr = r % 72;
        src = (wsel == 0) ? Wq : (wsel == 1) ? Wk : Wv;
        dst = wb + (size_t)wsel * (Hsz * Hsz);
        off = ((size_t)lr * 256 + tid) * 32;
    }
    #pragma unroll
    for (int c = 0; c < 4; ++c) {
        float4 a = *(const float4*)(src + off + c * 8);
        float4 b = *(const float4*)(src + off + c * 8 + 4);
        bf16x8 v;
        v[0] = (short)f2bf(a.x); v[1] = (short)f2bf(a.y);
        v[2] = (short)f2bf(a.z); v[3] = (short)f2bf(a.w);
        v[4] = (short)f2bf(b.x); v[5] = (short)f2bf(b.y);
        v[6] = (short)f2bf(b.z); v[7] = (short)f2bf(b.w);
        *(bf16x8*)(dst + off + c * 8) = v;
    }
}

// ---------------------------------------------------------------------------
// Kernel 1: QKV projection (round-11 datapath, XCD-chunked 1-D grid).
// ---------------------------------------------------------------------------
__global__ __launch_bounds__(256) void qkv_gemm(
    const u16* __restrict__ xb, const u16* __restrict__ wb,
    const float* __restrict__ bq, const float* __restrict__ bk,
    const float* __restrict__ bv,
    u16* __restrict__ q_ws, u16* __restrict__ k_ws, u16* __restrict__ vt_ws)
{
    const int tid = threadIdx.x;
    const int w = tid >> 6, l = tid & 63, lg = l >> 4, lh = l & 15;
    const int wg = blockIdx.x;                 // 0..1151
    const int swzb = (wg & 7) * 144 + (wg >> 3);
    const int nb = swzb % 18;
    const int m0 = (swzb / 18) * 128;
    const int z = nb / 6;
    const int n0l = (nb % 6) * 128;
    const u16* Wb = wb + (size_t)z * (Hsz * Hsz);
    const float* bias = (z == 0) ? bq : (z == 1) ? bk : bv;

    __shared__ __align__(16) u16 Xs[2][128 * 64];
    __shared__ __align__(16) u16 Ws[2][128 * 64];

    const int wm = w >> 1, wn = w & 1;

    f32x4 acc[4][4];
    #pragma unroll
    for (int i = 0; i < 4; ++i)
        #pragma unroll
        for (int j = 0; j < 4; ++j)
            acc[i][j] = (f32x4){0.f, 0.f, 0.f, 0.f};

    auto stage = [&](int buf, int k0) {
        #pragma unroll
        for (int p = 0; p < 4; ++p) {
            int id = w * 256 + p * 64 + l;
            int r = id >> 3, c8 = id & 7;
            int cswz = c8 ^ (r & 7);
            glds16(xb + (size_t)(m0 + r) * Hsz + k0 + cswz * 8,
                   &Xs[buf][(w * 256 + p * 64) * 8]);
            glds16(Wb + (size_t)(n0l + r) * Hsz + k0 + cswz * 8,
                   &Ws[buf][(w * 256 + p * 64) * 8]);
        }
    };

    stage(0, 0);
    asm volatile("s_waitcnt vmcnt(0)" ::: "memory");
    BAR();

    #pragma unroll 1
    for (int ks = 0; ks < 12; ++ks) {
        const int cur = ks & 1;
        if (ks < 11) {
            stage(cur ^ 1, (ks + 1) * 64);
            asm volatile("s_waitcnt vmcnt(8)" ::: "memory");
        } else {
            asm volatile("s_waitcnt vmcnt(0)" ::: "memory");
        }
        BAR();

        __builtin_amdgcn_s_setprio(1);
        #pragma unroll
        for (int s = 0; s < 2; ++s) {
            bf16x8 af[4], bfr[4];
            #pragma unroll
            for (int tq = 0; tq < 4; ++tq) {
                af[tq]  = LDSFRAG(Xs[cur], wm * 64 + tq * 16 + lh, 4 * s + lg);
                bfr[tq] = LDSFRAG(Ws[cur], wn * 64 + tq * 16 + lh, 4 * s + lg);
            }
            if (z <= 1) {
                #pragma unroll
                for (int mt = 0; mt < 4; ++mt)
                    #pragma unroll
                    for (int nt = 0; nt < 4; ++nt)
                        acc[mt][nt] = __builtin_amdgcn_mfma_f32_16x16x32_bf16(
                            bfr[nt], af[mt], acc[mt][nt], 0, 0, 0);
            } else {
                #pragma unroll
                for (int mt = 0; mt < 4; ++mt)
                    #pragma unroll
                    for (int nt = 0; nt < 4; ++nt)
                        acc[mt][nt] = __builtin_amdgcn_mfma_f32_16x16x32_bf16(
                            af[mt], bfr[nt], acc[mt][nt], 0, 0, 0);
            }
        }
        __builtin_amdgcn_s_setprio(0);
        BAR();
    }

    if (z <= 1) {
        u16* outp = (z == 0) ? q_ws : k_ws;
        #pragma unroll
        for (int mt = 0; mt < 4; ++mt) {
            int m = m0 + wm * 64 + mt * 16 + lh;
            int bb = m >> 11, t = m & 2047;
            #pragma unroll
            for (int nt = 0; nt < 4; ++nt) {
                int nbase = n0l + wn * 64 + nt * 16 + lg * 4;
                int hh = nbase >> 6, d0 = nbase & 63;
                f32x4 b4 = *(const f32x4*)(bias + nbase);
                u16x4 pk;
                #pragma unroll
                for (int r = 0; r < 4; ++r) pk[r] = f2bf(acc[mt][nt][r] + b4[r]);
                *(u16x4*)(outp + ((size_t)(bb * NHsz + hh) * Tsz + t) * HDsz + d0) = pk;
            }
        }
    } else {
        #pragma unroll
        for (int nt = 0; nt < 4; ++nt) {
            int nloc = n0l + wn * 64 + nt * 16 + lh;
            float bval = bias[nloc];
            int hh = nloc >> 6, d = nloc & 63;
            #pragma unroll
            for (int mt = 0; mt < 4; ++mt) {
                int t0m = m0 + wm * 64 + mt * 16 + lg * 4;
                int bb = t0m >> 11, t0 = t0m & 2047;
                u16x4 pk;
                #pragma unroll
                for (int r = 0; r < 4; ++r) pk[r] = f2bf(acc[mt][nt][r] + bval);
                *(u16x4*)(vt_ws + ((size_t)(bb * NHsz + hh) * HDsz + d) * Tsz + t0) = pk;
            }
        }
    }
}

// ---------------------------------------------------------------------------
// Kernel 2: causal flash attention — round-13 version VERBATIM (best: 82.6us).
// Merged kt loop over two Q-tiles (qt_hi=16+bx, qt_lo=15-bx); each K/V tile
// staged once. KVBLK=64, 128B-row chunk-XOR tiles, dbuf, counted vmcnt,
// LDS P round-trip, XCD-chunked block swizzle, online softmax + defer-rescale.
// ---------------------------------------------------------------------------
__global__ __launch_bounds__(256) void attn_mfma(
    const u16* __restrict__ q_ws, const u16* __restrict__ k_ws,
    const u16* __restrict__ vt_ws, const float* __restrict__ am,
    float* __restrict__ out)
{
    const int tid = threadIdx.x;
    const int w = tid >> 6, l = tid & 63, lg = l >> 4, lh = l & 15;
    const int wg = blockIdx.x;
    const int swz = (wg & 7) * 96 + (wg >> 3);
    const int bx = swz & 15;
    const int grp = swz >> 4;          // 0..47
    const int h = grp % NHsz, b = grp / NHsz;
    const int bh = b * NHsz + h;

    const u16* Qb = q_ws + (size_t)bh * Tsz * HDsz;
    const u16* Kb = k_ws + (size_t)bh * Tsz * HDsz;
    const u16* Vb = vt_ws + (size_t)bh * HDsz * Tsz;   // [d][t]
    const float* amb = am + (size_t)b * Tsz;

    __shared__ __align__(16) u16 Ks[2][64 * 64];
    __shared__ __align__(16) u16 Vs[2][64 * 64];       // [d][kv] layout
    __shared__ __align__(16) u16 Ps[4][16 * 64];       // per-wave, swizzled
    __shared__ __align__(16) float ambs[Tsz];

    const float LOG2E  = 1.44269504f;
    const float SCALE2 = 0.125f * 1.44269504f;
    const f32x4 zero4 = {0.f, 0.f, 0.f, 0.f};
    u16* myP = &Ps[w][0];
    const int srcbase = l & 0x30;
    const int qo = lg * 4;

    const int qt_hi = 16 + bx, qt_lo = 15 - bx;
    const int q0h = qt_hi * 64 + w * 16;
    const int q0l = qt_lo * 64 + w * 16;
    const int qrow_h = q0h + lh, qrow_l = q0l + lh;

    // ---- stage mask (8KB) + K/V tile 0 + Q fragments ----
    #pragma unroll
    for (int i = 0; i < 2; ++i)
        glds16(amb + (size_t)(i * 256 + tid) * 4, ambs + (i * 256 + w * 64) * 4);
    #pragma unroll
    for (int p = 0; p < 2; ++p) {
        int id = w * 128 + p * 64 + l;
        int r = id >> 3, c8 = id & 7;
        int cswz = c8 ^ (r & 7);
        glds16(Kb + (size_t)r * HDsz + cswz * 8, &Ks[0][(w * 128 + p * 64) * 8]);
        glds16(Vb + (size_t)r * Tsz + cswz * 8, &Vs[0][(w * 128 + p * 64) * 8]);
    }
    bf16x8 qfh0 = *(const bf16x8*)(Qb + (size_t)(q0h + lh) * HDsz + lg * 8);
    bf16x8 qfh1 = *(const bf16x8*)(Qb + (size_t)(q0h + lh) * HDsz + lg * 8 + 32);
    bf16x8 qfl0 = *(const bf16x8*)(Qb + (size_t)(q0l + lh) * HDsz + lg * 8);
    bf16x8 qfl1 = *(const bf16x8*)(Qb + (size_t)(q0l + lh) * HDsz + lg * 8 + 32);
    asm volatile("s_waitcnt vmcnt(0)" ::: "memory");
    __syncthreads();
    #pragma unroll
    for (int i = 0; i < 8; ++i) ambs[tid * 8 + i] *= LOG2E;
    __syncthreads();

    f32x4 oh[4], ol[4];
    #pragma unroll
    for (int n = 0; n < 4; ++n) { oh[n] = zero4; ol[n] = zero4; }
    float m2h = -1e30f, l2h = 0.f, m2l = -1e30f, l2l = 0.f;

    // one Q-tile phase against the staged tile [kv0, kv0+64)
    auto phase = [&](const bf16x8& qf0, const bf16x8& qf1, int qrow,
                     f32x4* o, float& m2, float& l2,
                     bool diag, const u16* Ksb, const u16* Vsb, int kv0) {
        // ---- S^T = K @ Q^T ----
        f32x4 st[4];
        __builtin_amdgcn_s_setprio(1);
        if (!diag) {
            #pragma unroll
            for (int n = 0; n < 4; ++n) {
                int row = n * 16 + lh;
                bf16x8 kf0 = LDSFRAG(Ksb, row, lg);
                bf16x8 kf1 = LDSFRAG(Ksb, row, 4 + lg);
                f32x4 c = __builtin_amdgcn_mfma_f32_16x16x32_bf16(kf0, qf0, zero4, 0, 0, 0);
                st[n] = __builtin_amdgcn_mfma_f32_16x16x32_bf16(kf1, qf1, c, 0, 0, 0);
            }
        } else {
            #pragma unroll
            for (int n = 0; n < 4; ++n) {
                st[n] = zero4;
                if (n <= w) {
                    int row = n * 16 + lh;
                    bf16x8 kf0 = LDSFRAG(Ksb, row, lg);
                    bf16x8 kf1 = LDSFRAG(Ksb, row, 4 + lg);
                    f32x4 c = __builtin_amdgcn_mfma_f32_16x16x32_bf16(kf0, qf0, zero4, 0, 0, 0);
                    st[n] = __builtin_amdgcn_mfma_f32_16x16x32_bf16(kf1, qf1, c, 0, 0, 0);
                }
            }
        }
        __builtin_amdgcn_s_setprio(0);

        // ---- in-lane softmax (log2 domain) ----
        float pvv[16];
        float mx = -1e30f;
        if (!diag) {
            #pragma unroll
            for (int n = 0; n < 4; ++n) {
                f32x4 a4 = *(const f32x4*)(ambs + kv0 + n * 16 + lg * 4);
                #pragma unroll
                for (int r = 0; r < 4; ++r) {
                    float sv = fmaf(st[n][r], SCALE2, a4[r]);
                    pvv[n * 4 + r] = sv;
                    mx = fmaxf(mx, sv);
                }
            }
        } else {
            #pragma unroll
            for (int n = 0; n < 4; ++n) {
                f32x4 a4 = *(const f32x4*)(ambs + kv0 + n * 16 + lg * 4);
                #pragma unroll
                for (int r = 0; r < 4; ++r) {
                    int kvj = kv0 + n * 16 + lg * 4 + r;
                    float sv = (kvj > qrow) ? -1e30f : fmaf(st[n][r], SCALE2, a4[r]);
                    pvv[n * 4 + r] = sv;
                    mx = fmaxf(mx, sv);
                }
            }
        }
        mx = fmaxf(mx, __shfl_xor(mx, 16));
        mx = fmaxf(mx, __shfl_xor(mx, 32));

        // ---- defer-rescale (T13) ----
        const bool norescale = __all(mx <= m2 + 8.0f);
        float mn = m2;
        if (!norescale) mn = fmaxf(m2, mx);

        float ps = 0.f;
        #pragma unroll
        for (int i = 0; i < 16; ++i) {
            float p = exp2f(pvv[i] - mn);
            pvv[i] = p;
            ps += p;
        }
        ps += __shfl_xor(ps, 16);
        ps += __shfl_xor(ps, 32);

        if (norescale) {
            l2 += ps;
        } else {
            float corr = exp2f(m2 - mn);
            m2 = mn;
            l2 = l2 * corr + ps;
            float co[4];
            #pragma unroll
            for (int r = 0; r < 4; ++r)
                co[r] = __shfl(corr, srcbase | (qo + r));
            #pragma unroll
            for (int n = 0; n < 4; ++n)
                #pragma unroll
                for (int r = 0; r < 4; ++r)
                    o[n][r] *= co[r];
        }

        // ---- write P (4x b64, chunk-XOR swizzled [16 q][64 kv]) ----
        #pragma unroll
        for (int n = 0; n < 4; ++n) {
            u16x4 v;
            v[0] = f2bf(pvv[n * 4 + 0]); v[1] = f2bf(pvv[n * 4 + 1]);
            v[2] = f2bf(pvv[n * 4 + 2]); v[3] = f2bf(pvv[n * 4 + 3]);
            int chunk = 2 * n + (lg >> 1);
            int byteoff = lh * 128 + ((chunk ^ (lh & 7)) << 4) + ((lg & 1) << 3);
            *(u16x4*)((char*)myP + byteoff) = v;
        }

        // ---- O += P V ----
        const int smaxv = (diag && w < 2) ? 0 : 1;
        __builtin_amdgcn_s_setprio(1);
        #pragma unroll
        for (int s = 0; s < 2; ++s) {
            if (s <= smaxv) {
                int chunk = (4 * s + lg) ^ (lh & 7);
                bf16x8 pf = *(const bf16x8*)((const char*)myP + lh * 128 + (chunk << 4));
                #pragma unroll
                for (int n = 0; n < 4; ++n) {
                    bf16x8 vf = LDSFRAG(Vsb, n * 16 + lh, 4 * s + lg);
                    o[n] = __builtin_amdgcn_mfma_f32_16x16x32_bf16(pf, vf, o[n], 0, 0, 0);
                }
            }
        }
        __builtin_amdgcn_s_setprio(0);
    };

    #pragma unroll 1
    for (int kt = 0; kt <= qt_hi; ++kt) {
        const int cur = kt & 1;
        const int kv0 = kt * 64;

        if (kt < qt_hi) {
            const int kv1 = kv0 + 64;
            #pragma unroll
            for (int p = 0; p < 2; ++p) {
                int id = w * 128 + p * 64 + l;
                int r = id >> 3, c8 = id & 7;
                int cswz = c8 ^ (r & 7);
                glds16(Kb + (size_t)(kv1 + r) * HDsz + cswz * 8,
                       &Ks[cur ^ 1][(w * 128 + p * 64) * 8]);
                glds16(Vb + (size_t)r * Tsz + kv1 + cswz * 8,
                       &Vs[cur ^ 1][(w * 128 + p * 64) * 8]);
            }
            asm volatile("s_waitcnt vmcnt(4)" ::: "memory");
        } else {
            asm volatile("s_waitcnt vmcnt(0)" ::: "memory");
        }
        BAR();   // tile kt staged, all waves

        const u16* Ksb = &Ks[cur][0];
        const u16* Vsb = &Vs[cur][0];

        // hi Q-tile: always active
        phase(qfh0, qfh1, qrow_h, oh, m2h, l2h, kt == qt_hi, Ksb, Vsb, kv0);
        // lo Q-tile: active while kt <= qt_lo (block-uniform predicate)
        if (kt <= qt_lo)
            phase(qfl0, qfl1, qrow_l, ol, m2l, l2l, kt == qt_lo, Ksb, Vsb, kv0);

        BAR();   // all reads of buf[cur] done before next prefetch overwrites
    }

    // ---- epilogue: both Q-tiles ----
    {
        float linv[4];
        #pragma unroll
        for (int r = 0; r < 4; ++r)
            linv[r] = 1.0f / __shfl(l2h, srcbase | (qo + r));
        float* ob = out + ((size_t)(b * Tsz + q0h + qo)) * Hsz + h * HDsz + lh;
        #pragma unroll
        for (int r = 0; r < 4; ++r)
            #pragma unroll
            for (int n = 0; n < 4; ++n)
                ob[r * Hsz + n * 16] = oh[n][r] * linv[r];
    }
    {
        float linv[4];
        #pragma unroll
        for (int r = 0; r < 4; ++r)
            linv[r] = 1.0f / __shfl(l2l, srcbase | (qo + r));
        float* ob = out + ((size_t)(b * Tsz + q0l + qo)) * Hsz + h * HDsz + lh;
        #pragma unroll
        for (int r = 0; r < 4; ++r)
            #pragma unroll
            for (int n = 0; n < 4; ++n)
                ob[r * Hsz + n * 16] = ol[n][r] * linv[r];
    }
}

extern "C" void kernel_launch(void* const* d_in, const int* in_sizes, int n_in,
                              void* d_out, int out_size, void* d_ws, size_t ws_size,
                              hipStream_t stream) {
    const float* X  = (const float*)d_in[0];
    const float* am = (const float*)d_in[1];
    const float* Wq = (const float*)d_in[2];
    const float* bq = (const float*)d_in[3];
    const float* Wk = (const float*)d_in[4];
    const float* bk = (const float*)d_in[5];
    const float* Wv = (const float*)d_in[6];
    const float* bv = (const float*)d_in[7];
    float* out = (float*)d_out;

    const size_t per = (size_t)8192 * Hsz;
    u16* q_ws  = (u16*)d_ws;
    u16* k_ws  = q_ws + per;
    u16* vt_ws = k_ws + per;

    u16* xb = (u16*)d_out;
    u16* wb = xb + per;

    to_bf16<<<dim3(984), 256, 0, stream>>>(X, Wq, Wk, Wv, xb, wb);

    qkv_gemm<<<dim3(1152), 256, 0, stream>>>(xb, wb, bq, bk, bv, q_ws, k_ws, vt_ws);

    attn_mfma<<<dim3(768), 256, 0, stream>>>(q_ws, k_ws, vt_ws, am, out);
}